// Round 10
// baseline (267.625 us; speedup 1.0000x reference)
//
#include <hip/hip_runtime.h>
#include <stdint.h>

typedef float  f32x4   __attribute__((ext_vector_type(4)));
typedef float  float4v __attribute__((ext_vector_type(4)));
typedef short  short4v __attribute__((ext_vector_type(4)));
typedef short  short8v __attribute__((ext_vector_type(8)));
typedef __bf16 bf16x8  __attribute__((ext_vector_type(8)));

static __device__ __forceinline__ short f2bf(float f) {
  unsigned u = __builtin_bit_cast(unsigned, f);
  u += 0x7FFFu + ((u >> 16) & 1u);
  return (short)(u >> 16);
}

static __device__ __forceinline__ f32x4 mfma16(short8v a, short8v b, f32x4 c) {
  return __builtin_amdgcn_mfma_f32_16x16x32_bf16(
      __builtin_bit_cast(bf16x8, a), __builtin_bit_cast(bf16x8, b), c, 0, 0, 0);
}

static __device__ __forceinline__ short8v cat44(short4v a, short4v b) {
  short8v r;
  r[0] = a[0]; r[1] = a[1]; r[2] = a[2]; r[3] = a[3];
  r[4] = b[0]; r[5] = b[1]; r[6] = b[2]; r[7] = b[3];
  return r;
}

// Prelude A: convert qkv_w (384x128) and proj_w (128x128) f32 -> bf16.
__global__ void cvt_weights_kernel(const float* __restrict__ qkv_w,
                                   const float* __restrict__ proj_w,
                                   short* __restrict__ wq, short* __restrict__ wp) {
  int i = blockIdx.x * 256 + threadIdx.x;   // grid = 192 blocks -> 49152
  wq[i] = f2bf(qkv_w[i]);
  if (i < 16384) wp[i] = f2bf(proj_w[i]);
}

// Prelude B: combined bias+mask table laid out as the MFMA S-fragment:
// cmb[w(64)][h(4)][qt(4)][i(4)][lane(64)][r(4)] f32  (4 MB)
__global__ void build_cmb_kernel(const float* __restrict__ mask,
                                 const float* __restrict__ bias_table,
                                 float* __restrict__ cmb) {
  int id   = blockIdx.x * 256 + threadIdx.x;   // grid = 1024 blocks
  int lane = id & 63;
  int i    = (id >> 6) & 3;
  int qt   = (id >> 8) & 3;
  int h    = (id >> 10) & 3;
  int w    = id >> 12;
  int q     = qt * 16 + (lane & 15);
  int kbase = i * 16 + ((lane >> 4) << 2);
  f32x4 v;
#pragma unroll
  for (int r = 0; r < 4; ++r) {
    int key = kbase + r;
    float val;
    if (key >= 49) {
      val = -1e30f;
    } else if (q >= 49) {
      val = 0.f;
    } else {
      int qi = q / 7, qj = q - qi * 7;
      int ki = key / 7, kj = key - ki * 7;
      int ridx = (qi - ki + 6) * 13 + (qj - kj + 6);
      val = bias_table[ridx * 4 + h] + mask[w * 2401 + q * 49 + key];
    }
    v[r] = val;
  }
  ((f32x4*)cmb)[id] = v;
}

// Kernel 1: QKV projection. One block = one window, 8 waves (g,h).
// Writes per window (24576 shorts): q [4h][64t][32d] (scaled bf16) at +0,
// k same at +8192, v^T [4h][32d][64t] at +16384 (via LDS bounce, coalesced).
__global__ __launch_bounds__(512, 4)
void qkv_kernel(const float* __restrict__ x,
                const float* __restrict__ qkv_b,
                const short* __restrict__ wq,
                short* __restrict__ qkv, int win0) {
  __shared__ __align__(16) short smem[17920];
  short* xb  = smem;            // [64][136]
  short* vtm = smem + 8704;     // [4][32][72]

  const int b    = blockIdx.x;
  const int tid  = threadIdx.x;
  const int lane = tid & 63;
  const int wv   = tid >> 6;
  const int h    = wv & 3;
  const int g    = wv >> 2;
  const int l15  = lane & 15;
  const int lhi  = lane >> 4;
  const int cb   = lhi * 8;

  // stage x -> bf16 LDS, zero pad rows 49..63
  {
    short4v z = {0, 0, 0, 0};
    for (int idx = tid; idx < 510; idx += 512)
      *(short4v*)&xb[49 * 136 + idx * 4] = z;
    const float* xw = x + (long)(win0 + b) * (49 * 128);
    for (int idx = tid; idx < 1568; idx += 512) {
      int m  = idx >> 5;
      int c0 = (idx & 31) << 2;
      float4v v = *(const float4v*)&xw[m * 128 + c0];
      short4v s;
      s[0] = f2bf(v[0]); s[1] = f2bf(v[1]); s[2] = f2bf(v[2]); s[3] = f2bf(v[3]);
      *(short4v*)&xb[m * 136 + c0] = s;
    }
  }
  __syncthreads();

  short* qg = qkv + (long)b * 24576;

  // fused Q,K (swapped acc = [wcol][token]) + V (normal acc = [token][dcol])
  {
    f32x4 qk[2][2][2];   // [mat][nt][jt]
    f32x4 av[2][2];      // [nt][mt]
#pragma unroll
    for (int mat = 0; mat < 2; ++mat)
#pragma unroll
      for (int nt = 0; nt < 2; ++nt) {
        const f32x4 bias4 = *(const f32x4*)&qkv_b[mat * 128 + h * 32 + nt * 16 + lhi * 4];
        qk[mat][nt][0] = bias4;
        qk[mat][nt][1] = bias4;
      }
#pragma unroll
    for (int nt = 0; nt < 2; ++nt) {
      const float vb = qkv_b[256 + h * 32 + nt * 16 + l15];
      av[nt][0] = f32x4{vb, vb, vb, vb};
      av[nt][1] = av[nt][0];
    }

#pragma unroll
    for (int ks = 0; ks < 4; ++ks) {
      const short8v a0 = *(const short8v*)&xb[(g * 32 + l15) * 136 + ks * 32 + cb];
      const short8v a1 = *(const short8v*)&xb[(g * 32 + 16 + l15) * 136 + ks * 32 + cb];
#pragma unroll
      for (int nt = 0; nt < 2; ++nt) {
        const short8v bq =
            *(const short8v*)&wq[(h * 32 + nt * 16 + l15) * 128 + ks * 32 + cb];
        const short8v bk =
            *(const short8v*)&wq[(128 + h * 32 + nt * 16 + l15) * 128 + ks * 32 + cb];
        const short8v bv =
            *(const short8v*)&wq[(256 + h * 32 + nt * 16 + l15) * 128 + ks * 32 + cb];
        qk[0][nt][0] = mfma16(bq, a0, qk[0][nt][0]);
        qk[0][nt][1] = mfma16(bq, a1, qk[0][nt][1]);
        qk[1][nt][0] = mfma16(bk, a0, qk[1][nt][0]);
        qk[1][nt][1] = mfma16(bk, a1, qk[1][nt][1]);
        av[nt][0]    = mfma16(a0, bv, av[nt][0]);
        av[nt][1]    = mfma16(a1, bv, av[nt][1]);
      }
    }

    const float scale = 0.1767766952966369f;  // 32^-0.5 baked into Q
#pragma unroll
    for (int jt = 0; jt < 2; ++jt)
#pragma unroll
      for (int nt = 0; nt < 2; ++nt) {
        short4v pq, pk;
#pragma unroll
        for (int r = 0; r < 4; ++r) {
          pq[r] = f2bf(qk[0][nt][jt][r] * scale);
          pk[r] = f2bf(qk[1][nt][jt][r]);
        }
        const int toff = (h * 64 + g * 32 + jt * 16 + l15) * 32 + nt * 16 + lhi * 4;
        *(short4v*)&qg[toff]        = pq;
        *(short4v*)&qg[8192 + toff] = pk;
      }

#pragma unroll
    for (int nt = 0; nt < 2; ++nt)
#pragma unroll
      for (int mt = 0; mt < 2; ++mt) {
        short4v p;
#pragma unroll
        for (int r = 0; r < 4; ++r) p[r] = f2bf(av[nt][mt][r]);
        *(short4v*)&vtm[h * 2304 + (nt * 16 + l15) * 72 + g * 32 + mt * 16 + lhi * 4] = p;
      }
  }
  __syncthreads();

  // coalesced copy vtm -> global v^T [4][32][64]
#pragma unroll
  for (int it = 0; it < 2; ++it) {
    const int c   = tid + it * 512;
    const int h_  = c >> 8;
    const int rem = c & 255;
    const int dd  = rem >> 3;
    const int tc  = (rem & 7) * 8;
    *(short8v*)&qg[16384 + (h_ * 32 + dd) * 64 + tc] =
        *(const short8v*)&vtm[h_ * 2304 + dd * 72 + tc];
  }
}

// Kernel 2: attention + output projection. One block = one window, 8 waves
// (g,h). All q/k/v loads are direct coalesced global reads; zero barriers
// until the single aom->proj one. LDS = aom only (17408 B).
__global__ __launch_bounds__(512, 5)
void attn_kernel(const short* __restrict__ qkv,
                 const float* __restrict__ proj_b,
                 const short* __restrict__ wp,
                 const float* __restrict__ cmb,
                 float* __restrict__ out, int win0) {
  __shared__ __align__(16) short aom[8704];   // [64][136]

  const int b    = blockIdx.x;
  const int tid  = threadIdx.x;
  const int lane = tid & 63;
  const int wv   = tid >> 6;
  const int h    = wv & 3;
  const int g    = wv >> 2;
  const int l15  = lane & 15;
  const int lhi  = lane >> 4;
  const int cb   = lhi * 8;

  const short* qg = qkv + (long)b * 24576;
  const int w = win0 + b;

  {
    short8v kfr[4], qfr[2];
#pragma unroll
    for (int i = 0; i < 4; ++i)
      kfr[i] = *(const short8v*)&qg[8192 + (h * 64 + i * 16 + l15) * 32 + lhi * 8];
#pragma unroll
    for (int jt = 0; jt < 2; ++jt)
      qfr[jt] = *(const short8v*)&qg[(h * 64 + g * 32 + jt * 16 + l15) * 32 + lhi * 8];

    const f32x4* cmb4 = (const f32x4*)cmb;
    const long cbase = (long)(w & 63) * 4096 + h * 1024 + g * 512 + lane;

#pragma unroll
    for (int jt = 0; jt < 2; ++jt) {
      f32x4 s[4];
#pragma unroll
      for (int i = 0; i < 4; ++i)
        s[i] = mfma16(kfr[i], qfr[jt], cmb4[cbase + jt * 256 + i * 64]);

      float mx = s[0][0];
#pragma unroll
      for (int i = 0; i < 4; ++i)
#pragma unroll
        for (int r = 0; r < 4; ++r) mx = fmaxf(mx, s[i][r]);
      mx = fmaxf(mx, __shfl_xor(mx, 16));
      mx = fmaxf(mx, __shfl_xor(mx, 32));
      float sum = 0.f;
#pragma unroll
      for (int i = 0; i < 4; ++i)
#pragma unroll
        for (int r = 0; r < 4; ++r) {
          float e = __expf(s[i][r] - mx);
          s[i][r] = e;
          sum += e;
        }
      sum += __shfl_xor(sum, 16);
      sum += __shfl_xor(sum, 32);
      const float inv = 1.f / sum;

      short8v pb[2];
#pragma unroll
      for (int ks = 0; ks < 2; ++ks) {
        short8v pv;
#pragma unroll
        for (int e = 0; e < 4; ++e) pv[e]     = f2bf(s[2 * ks][e] * inv);
#pragma unroll
        for (int e = 0; e < 4; ++e) pv[4 + e] = f2bf(s[2 * ks + 1][e] * inv);
        pb[ks] = pv;
      }

#pragma unroll
      for (int dt = 0; dt < 2; ++dt) {
        f32x4 o = {0.f, 0.f, 0.f, 0.f};
#pragma unroll
        for (int ks = 0; ks < 2; ++ks) {
          const int va = 16384 + (h * 32 + dt * 16 + l15) * 64 + ks * 32 + lhi * 4;
          short8v vfr = cat44(*(const short4v*)&qg[va], *(const short4v*)&qg[va + 16]);
          o = mfma16(vfr, pb[ks], o);
        }
        short4v p;
#pragma unroll
        for (int r = 0; r < 4; ++r) p[r] = f2bf(o[r]);
        *(short4v*)&aom[(g * 32 + jt * 16 + l15) * 136 + h * 32 + dt * 16 + lhi * 4] = p;
      }
    }
  }
  __syncthreads();

  // output projection Y = AO @ proj_w^T + proj_b (ks-outer)
  {
    f32x4 po[2][2];      // [nt][mt]
#pragma unroll
    for (int nt = 0; nt < 2; ++nt) {
      const float pbv = proj_b[h * 32 + nt * 16 + l15];
      po[nt][0] = f32x4{pbv, pbv, pbv, pbv};
      po[nt][1] = po[nt][0];
    }
#pragma unroll
    for (int ks = 0; ks < 4; ++ks) {
      const short8v p0 = *(const short8v*)&aom[(g * 32 + l15) * 136 + ks * 32 + cb];
      const short8v p1 = *(const short8v*)&aom[(g * 32 + 16 + l15) * 136 + ks * 32 + cb];
#pragma unroll
      for (int nt = 0; nt < 2; ++nt) {
        const short8v wfr =
            *(const short8v*)&wp[(h * 32 + nt * 16 + l15) * 128 + ks * 32 + cb];
        po[nt][0] = mfma16(p0, wfr, po[nt][0]);
        po[nt][1] = mfma16(p1, wfr, po[nt][1]);
      }
    }
    float* outw = out + (long)w * (49 * 128);
#pragma unroll
    for (int nt = 0; nt < 2; ++nt) {
      const int ncol = h * 32 + nt * 16 + l15;
#pragma unroll
      for (int r = 0; r < 4; ++r) {
        const int m0 = g * 32 + lhi * 4 + r;
        if (m0 < 49) outw[m0 * 128 + ncol] = po[nt][0][r];
        const int m1 = m0 + 16;
        if (m1 < 49) outw[m1 * 128 + ncol] = po[nt][1][r];
      }
    }
  }
}

extern "C" void kernel_launch(void* const* d_in, const int* in_sizes, int n_in,
                              void* d_out, int out_size, void* d_ws, size_t ws_size,
                              hipStream_t stream) {
  const float* x          = (const float*)d_in[0];
  const float* mask       = (const float*)d_in[1];
  const float* qkv_w      = (const float*)d_in[2];
  const float* qkv_b      = (const float*)d_in[3];
  const float* proj_w     = (const float*)d_in[4];
  const float* proj_b     = (const float*)d_in[5];
  const float* bias_table = (const float*)d_in[6];

  short* wq   = (short*)d_ws;                        // 384*128 bf16 (98304 B)
  short* wp   = wq + 49152;                          // 128*128 bf16 (32768 B)
  float* cmb  = (float*)((char*)d_ws + 131072);      // 4 MB combined bias+mask
  short* qkvb = (short*)((char*)d_ws + 4456448);     // qkv scratch (48 KB/window)

  cvt_weights_kernel<<<dim3(192), dim3(256), 0, stream>>>(qkv_w, proj_w, wq, wp);
  build_cmb_kernel<<<dim3(1024), dim3(256), 0, stream>>>(mask, bias_table, cmb);

  // Chunk windows so the qkv intermediate fits the provided workspace.
  const long per_win = 49152;                         // bytes per window
  long avail = (long)ws_size - 4456448L;
  int cw = 4096;
  if (avail < 4096L * per_win) {
    cw = (int)(avail / per_win);
    if (cw < 1) cw = 1;
    if (cw > 4096) cw = 4096;
  }
  for (int w0 = 0; w0 < 4096; w0 += cw) {
    int n = 4096 - w0 < cw ? 4096 - w0 : cw;
    qkv_kernel<<<dim3(n), dim3(512), 0, stream>>>(x, qkv_b, wq, qkvb, w0);
    attn_kernel<<<dim3(n), dim3(512), 0, stream>>>(qkvb, proj_b, wp, cmb,
                                                   (float*)d_out, w0);
  }
}

// Round 11
// 256.304 us; speedup vs baseline: 1.0442x; 1.0442x over previous
//
#include <hip/hip_runtime.h>
#include <stdint.h>

typedef float  f32x4   __attribute__((ext_vector_type(4)));
typedef float  float4v __attribute__((ext_vector_type(4)));
typedef short  short4v __attribute__((ext_vector_type(4)));
typedef short  short8v __attribute__((ext_vector_type(8)));
typedef __bf16 bf16x8  __attribute__((ext_vector_type(8)));

static __device__ __forceinline__ short f2bf(float f) {
  unsigned u = __builtin_bit_cast(unsigned, f);
  u += 0x7FFFu + ((u >> 16) & 1u);
  return (short)(u >> 16);
}

static __device__ __forceinline__ f32x4 mfma16(short8v a, short8v b, f32x4 c) {
  return __builtin_amdgcn_mfma_f32_16x16x32_bf16(
      __builtin_bit_cast(bf16x8, a), __builtin_bit_cast(bf16x8, b), c, 0, 0, 0);
}

static __device__ __forceinline__ short8v cat44(short4v a, short4v b) {
  short8v r;
  r[0] = a[0]; r[1] = a[1]; r[2] = a[2]; r[3] = a[3];
  r[4] = b[0]; r[5] = b[1]; r[6] = b[2]; r[7] = b[3];
  return r;
}

// Prelude A: convert qkv_w (384x128) and proj_w (128x128) f32 -> bf16.
__global__ void cvt_weights_kernel(const float* __restrict__ qkv_w,
                                   const float* __restrict__ proj_w,
                                   short* __restrict__ wq, short* __restrict__ wp) {
  int i = blockIdx.x * 256 + threadIdx.x;   // grid = 192 blocks -> 49152
  wq[i] = f2bf(qkv_w[i]);
  if (i < 16384) wp[i] = f2bf(proj_w[i]);
}

// Prelude B: combined bias+mask table laid out as the MFMA S-fragment:
// cmb[w(64)][h(4)][qt(4)][i(4)][lane(64)][r(4)] f32  (4 MB)
__global__ void build_cmb_kernel(const float* __restrict__ mask,
                                 const float* __restrict__ bias_table,
                                 float* __restrict__ cmb) {
  int id   = blockIdx.x * 256 + threadIdx.x;   // grid = 1024 blocks
  int lane = id & 63;
  int i    = (id >> 6) & 3;
  int qt   = (id >> 8) & 3;
  int h    = (id >> 10) & 3;
  int w    = id >> 12;
  int q     = qt * 16 + (lane & 15);
  int kbase = i * 16 + ((lane >> 4) << 2);
  f32x4 v;
#pragma unroll
  for (int r = 0; r < 4; ++r) {
    int key = kbase + r;
    float val;
    if (key >= 49) {
      val = -1e30f;
    } else if (q >= 49) {
      val = 0.f;
    } else {
      int qi = q / 7, qj = q - qi * 7;
      int ki = key / 7, kj = key - ki * 7;
      int ridx = (qi - ki + 6) * 13 + (qj - kj + 6);
      val = bias_table[ridx * 4 + h] + mask[w * 2401 + q * 49 + key];
    }
    v[r] = val;
  }
  ((f32x4*)cmb)[id] = v;
}

// Kernel 1: QKV projection, 8 windows per block. 768 threads = 12 waves, one
// per (mat 0..2, head 0..3). Swapped orientation everywhere (acc rows = out
// dim, cols = token): q,k stored [win][64tok][128d] bf16, v stored directly
// transposed [win][128d][64tok]. Double-buffered x staging, 1 barrier/window.
__global__ __launch_bounds__(768, 3)
void qkv_pass(const float* __restrict__ x,
              const float* __restrict__ qkv_b,
              const short* __restrict__ wq,
              short* __restrict__ qb, short* __restrict__ kb,
              short* __restrict__ vt, int win0, int nwin) {
  __shared__ __align__(16) short xb[2][8704];   // [64][136] each

  const int tid  = threadIdx.x;
  const int lane = tid & 63;
  const int wv   = tid >> 6;     // 0..11
  const int mat  = wv >> 2;      // 0..2
  const int h    = wv & 3;
  const int l15  = lane & 15;
  const int lhi  = lane >> 4;
  const int cb   = lhi * 8;
  const int wbase = blockIdx.x * 8;
  const float scale = 0.1767766952966369f;  // 32^-0.5 baked into Q

#define STAGE(BUF, W)                                                        \
  do {                                                                       \
    int w_ = (W);                                                            \
    if (wbase + w_ < nwin) {                                                 \
      short* dst = xb[BUF];                                                  \
      short4v z = {0, 0, 0, 0};                                              \
      for (int i = tid; i < 510; i += 768)                                   \
        *(short4v*)&dst[49 * 136 + i * 4] = z;                               \
      const float* xw = x + (long)(win0 + wbase + w_) * 6272;                \
      for (int i = tid; i < 1568; i += 768) {                                \
        int m = i >> 5, c0 = (i & 31) << 2;                                  \
        float4v v = *(const float4v*)&xw[m * 128 + c0];                      \
        short4v s;                                                           \
        s[0] = f2bf(v[0]); s[1] = f2bf(v[1]);                                \
        s[2] = f2bf(v[2]); s[3] = f2bf(v[3]);                                \
        *(short4v*)&dst[m * 136 + c0] = s;                                   \
      }                                                                      \
    }                                                                        \
  } while (0)

  STAGE(0, 0);
  __syncthreads();

  for (int w = 0; w < 8; ++w) {
    if (w + 1 < 8) STAGE((w + 1) & 1, w + 1);

    if (wbase + w < nwin) {
      const short* src = xb[w & 1];
      f32x4 acc[2][4];   // [nt][jt]
#pragma unroll
      for (int nt = 0; nt < 2; ++nt) {
        const f32x4 bias4 =
            *(const f32x4*)&qkv_b[mat * 128 + h * 32 + nt * 16 + lhi * 4];
#pragma unroll
        for (int jt = 0; jt < 4; ++jt) acc[nt][jt] = bias4;
      }
#pragma unroll
      for (int ks = 0; ks < 4; ++ks) {
        short8v a[4];
#pragma unroll
        for (int jt = 0; jt < 4; ++jt)
          a[jt] = *(const short8v*)&src[(jt * 16 + l15) * 136 + ks * 32 + cb];
#pragma unroll
        for (int nt = 0; nt < 2; ++nt) {
          const short8v bfr = *(const short8v*)
              &wq[(mat * 128 + h * 32 + nt * 16 + l15) * 128 + ks * 32 + cb];
#pragma unroll
          for (int jt = 0; jt < 4; ++jt)
            acc[nt][jt] = mfma16(bfr, a[jt], acc[nt][jt]);
        }
      }
      const long w64 = (long)(wbase + w) * 64;
      if (mat == 2) {
        // v^T scatter: row = d (128-major), col = token
#pragma unroll
        for (int nt = 0; nt < 2; ++nt)
#pragma unroll
          for (int jt = 0; jt < 4; ++jt)
#pragma unroll
            for (int r = 0; r < 4; ++r)
              vt[((long)(wbase + w) * 128 + h * 32 + nt * 16 + lhi * 4 + r) * 64 +
                 jt * 16 + l15] = f2bf(acc[nt][jt][r]);
      } else {
        short* dstq = (mat == 0) ? qb : kb;
        const float mul = (mat == 0) ? scale : 1.0f;
#pragma unroll
        for (int nt = 0; nt < 2; ++nt)
#pragma unroll
          for (int jt = 0; jt < 4; ++jt) {
            short4v p;
#pragma unroll
            for (int r = 0; r < 4; ++r) p[r] = f2bf(acc[nt][jt][r] * mul);
            *(short4v*)&dstq[(w64 + jt * 16 + l15) * 128 + h * 32 + nt * 16 +
                             lhi * 4] = p;
          }
      }
    }
    __syncthreads();
  }
#undef STAGE
}

// Kernel 2: attention, one wave per (win, h, g). Zero barriers, zero LDS.
// AO overwrites Q in place (each wave touches only its own (h,g) slice).
__global__ __launch_bounds__(256, 3)
void attn_pass(short* __restrict__ qb,          // q in, attn-out in place
               const short* __restrict__ kb,
               const short* __restrict__ vt,
               const float* __restrict__ cmb, int win0, int nwin) {
  const int gw   = blockIdx.x * 4 + (threadIdx.x >> 6);
  const int lane = threadIdx.x & 63;
  const int l15  = lane & 15;
  const int lhi  = lane >> 4;
  const int w    = gw >> 3;
  if (w >= nwin) return;
  const int h = (gw >> 1) & 3;
  const int g = gw & 1;
  const long w64 = (long)w * 64;

  short8v kfr[4], qfr[2], vfr[2][2];
#pragma unroll
  for (int i = 0; i < 4; ++i)
    kfr[i] = *(const short8v*)&kb[(w64 + i * 16 + l15) * 128 + h * 32 + lhi * 8];
#pragma unroll
  for (int jt = 0; jt < 2; ++jt)
    qfr[jt] = *(const short8v*)
        &qb[(w64 + g * 32 + jt * 16 + l15) * 128 + h * 32 + lhi * 8];
#pragma unroll
  for (int dt = 0; dt < 2; ++dt)
#pragma unroll
    for (int ks = 0; ks < 2; ++ks) {
      const long va =
          ((long)w * 128 + h * 32 + dt * 16 + l15) * 64 + ks * 32 + lhi * 4;
      vfr[dt][ks] = cat44(*(const short4v*)&vt[va], *(const short4v*)&vt[va + 16]);
    }

  const f32x4* cmb4 = (const f32x4*)cmb;
  const long cbase = (long)((win0 + w) & 63) * 4096 + h * 1024 + g * 512 + lane;

#pragma unroll
  for (int jt = 0; jt < 2; ++jt) {
    f32x4 s[4];
#pragma unroll
    for (int i = 0; i < 4; ++i)
      s[i] = mfma16(kfr[i], qfr[jt], cmb4[cbase + jt * 256 + i * 64]);

    float mx = s[0][0];
#pragma unroll
    for (int i = 0; i < 4; ++i)
#pragma unroll
      for (int r = 0; r < 4; ++r) mx = fmaxf(mx, s[i][r]);
    mx = fmaxf(mx, __shfl_xor(mx, 16));
    mx = fmaxf(mx, __shfl_xor(mx, 32));
    float sum = 0.f;
#pragma unroll
    for (int i = 0; i < 4; ++i)
#pragma unroll
      for (int r = 0; r < 4; ++r) {
        float e = __expf(s[i][r] - mx);
        s[i][r] = e;
        sum += e;
      }
    sum += __shfl_xor(sum, 16);
    sum += __shfl_xor(sum, 32);
    const float inv = 1.f / sum;

    short8v pb[2];
#pragma unroll
    for (int ks = 0; ks < 2; ++ks) {
      short8v pv;
#pragma unroll
      for (int e = 0; e < 4; ++e) pv[e]     = f2bf(s[2 * ks][e] * inv);
#pragma unroll
      for (int e = 0; e < 4; ++e) pv[4 + e] = f2bf(s[2 * ks + 1][e] * inv);
      pb[ks] = pv;
    }

#pragma unroll
    for (int dt = 0; dt < 2; ++dt) {
      f32x4 o = {0.f, 0.f, 0.f, 0.f};
#pragma unroll
      for (int ks = 0; ks < 2; ++ks) o = mfma16(vfr[dt][ks], pb[ks], o);
      short4v p;
#pragma unroll
      for (int r = 0; r < 4; ++r) p[r] = f2bf(o[r]);
      *(short4v*)&qb[(w64 + g * 32 + jt * 16 + l15) * 128 + h * 32 + dt * 16 +
                     lhi * 4] = p;
    }
  }
}

// Kernel 3: output projection, one wave per (win, 32-col group). No barriers,
// no LDS. Y = AO @ proj_w^T + proj_b, f32 out for tokens < 49.
__global__ __launch_bounds__(256, 4)
void proj_pass(const short* __restrict__ ao,    // = qb (attn out in place)
               const float* __restrict__ proj_b,
               const short* __restrict__ wp,
               float* __restrict__ out, int win0, int nwin) {
  const int gw   = blockIdx.x * 4 + (threadIdx.x >> 6);
  const int lane = threadIdx.x & 63;
  const int l15  = lane & 15;
  const int lhi  = lane >> 4;
  const int w    = gw >> 2;
  if (w >= nwin) return;
  const int cg = gw & 3;
  const long w64 = (long)w * 64;

  f32x4 po[2][4];   // [nt][jt]
#pragma unroll
  for (int nt = 0; nt < 2; ++nt) {
    const float pbv = proj_b[cg * 32 + nt * 16 + l15];
#pragma unroll
    for (int jt = 0; jt < 4; ++jt) po[nt][jt] = f32x4{pbv, pbv, pbv, pbv};
  }
#pragma unroll
  for (int ks = 0; ks < 4; ++ks) {
    short8v a[4];
#pragma unroll
    for (int jt = 0; jt < 4; ++jt)
      a[jt] = *(const short8v*)&ao[(w64 + jt * 16 + l15) * 128 + ks * 32 + lhi * 8];
#pragma unroll
    for (int nt = 0; nt < 2; ++nt) {
      const short8v wfr = *(const short8v*)
          &wp[(cg * 32 + nt * 16 + l15) * 128 + ks * 32 + lhi * 8];
#pragma unroll
      for (int jt = 0; jt < 4; ++jt) po[nt][jt] = mfma16(a[jt], wfr, po[nt][jt]);
    }
  }
  float* outw = out + (long)(win0 + w) * (49 * 128);
#pragma unroll
  for (int nt = 0; nt < 2; ++nt) {
    const int ncol = cg * 32 + nt * 16 + l15;
#pragma unroll
    for (int jt = 0; jt < 4; ++jt)
#pragma unroll
      for (int r = 0; r < 4; ++r) {
        const int tok = jt * 16 + lhi * 4 + r;
        if (tok < 49) outw[tok * 128 + ncol] = po[nt][jt][r];
      }
  }
}

extern "C" void kernel_launch(void* const* d_in, const int* in_sizes, int n_in,
                              void* d_out, int out_size, void* d_ws, size_t ws_size,
                              hipStream_t stream) {
  const float* x          = (const float*)d_in[0];
  const float* mask       = (const float*)d_in[1];
  const float* qkv_w      = (const float*)d_in[2];
  const float* qkv_b      = (const float*)d_in[3];
  const float* proj_w     = (const float*)d_in[4];
  const float* proj_b     = (const float*)d_in[5];
  const float* bias_table = (const float*)d_in[6];

  short* wq  = (short*)d_ws;                         // 384*128 bf16 (98304 B)
  short* wp  = wq + 49152;                           // 128*128 bf16 (32768 B)
  float* cmb = (float*)((char*)d_ws + 131072);       // 4 MB combined bias+mask
  char*  buf = (char*)d_ws + 4325376;                // per-window q/k/vt

  cvt_weights_kernel<<<dim3(192), dim3(256), 0, stream>>>(qkv_w, proj_w, wq, wp);
  build_cmb_kernel<<<dim3(1024), dim3(256), 0, stream>>>(mask, bias_table, cmb);

  // Per window: q 16384 B + k 16384 B + vt 16384 B = 49152 B.
  long avail = (long)ws_size - 4325376L;
  int cw = 4096;
  if (avail < 4096L * 49152L) {
    cw = (int)(avail / 49152L) & ~7;     // multiple of 8 for qkv_pass
    if (cw < 8) cw = 8;
    if (cw > 4096) cw = 4096;
  }
  for (int w0 = 0; w0 < 4096; w0 += cw) {
    const int n = (4096 - w0 < cw) ? (4096 - w0) : cw;
    short* qb = (short*)buf;
    short* kb = qb + (long)cw * 8192;
    short* vt = kb + (long)cw * 8192;
    qkv_pass<<<dim3((n + 7) / 8), dim3(768), 0, stream>>>(
        x, qkv_b, wq, qb, kb, vt, w0, n);
    attn_pass<<<dim3(n * 2), dim3(256), 0, stream>>>(qb, kb, vt, cmb, w0, n);
    proj_pass<<<dim3(n), dim3(256), 0, stream>>>(qb, proj_b, wp,
                                                 (float*)d_out, w0, n);
  }
}

// Round 12
// 116.990 us; speedup vs baseline: 2.2876x; 2.1908x over previous
//
#include <hip/hip_runtime.h>
#include <stdint.h>

typedef float  f32x4   __attribute__((ext_vector_type(4)));
typedef float  float4v __attribute__((ext_vector_type(4)));
typedef short  short4v __attribute__((ext_vector_type(4)));
typedef short  short8v __attribute__((ext_vector_type(8)));
typedef __bf16 bf16x8  __attribute__((ext_vector_type(8)));

static __device__ __forceinline__ short f2bf(float f) {
  unsigned u = __builtin_bit_cast(unsigned, f);
  u += 0x7FFFu + ((u >> 16) & 1u);
  return (short)(u >> 16);
}

static __device__ __forceinline__ f32x4 mfma16(short8v a, short8v b, f32x4 c) {
  return __builtin_amdgcn_mfma_f32_16x16x32_bf16(
      __builtin_bit_cast(bf16x8, a), __builtin_bit_cast(bf16x8, b), c, 0, 0, 0);
}

static __device__ __forceinline__ short8v cat44(short4v a, short4v b) {
  short8v r;
  r[0] = a[0]; r[1] = a[1]; r[2] = a[2]; r[3] = a[3];
  r[4] = b[0]; r[5] = b[1]; r[6] = b[2]; r[7] = b[3];
  return r;
}

// Prelude A: convert qkv_w (384x128) and proj_w (128x128) f32 -> bf16.
__global__ void cvt_weights_kernel(const float* __restrict__ qkv_w,
                                   const float* __restrict__ proj_w,
                                   short* __restrict__ wq, short* __restrict__ wp) {
  int i = blockIdx.x * 256 + threadIdx.x;   // grid = 192 blocks -> 49152
  wq[i] = f2bf(qkv_w[i]);
  if (i < 16384) wp[i] = f2bf(proj_w[i]);
}

// Prelude B: combined bias+mask table laid out as the MFMA S-fragment:
// cmb[w(64)][h(4)][qt(4)][i(4)][lane(64)][r(4)] f32  (4 MB)
__global__ void build_cmb_kernel(const float* __restrict__ mask,
                                 const float* __restrict__ bias_table,
                                 float* __restrict__ cmb) {
  int id   = blockIdx.x * 256 + threadIdx.x;   // grid = 1024 blocks
  int lane = id & 63;
  int i    = (id >> 6) & 3;
  int qt   = (id >> 8) & 3;
  int h    = (id >> 10) & 3;
  int w    = id >> 12;
  int q     = qt * 16 + (lane & 15);
  int kbase = i * 16 + ((lane >> 4) << 2);
  f32x4 v;
#pragma unroll
  for (int r = 0; r < 4; ++r) {
    int key = kbase + r;
    float val;
    if (key >= 49) {
      val = -1e30f;
    } else if (q >= 49) {
      val = 0.f;
    } else {
      int qi = q / 7, qj = q - qi * 7;
      int ki = key / 7, kj = key - ki * 7;
      int ridx = (qi - ki + 6) * 13 + (qj - kj + 6);
      val = bias_table[ridx * 4 + h] + mask[w * 2401 + q * 49 + key];
    }
    v[r] = val;
  }
  ((f32x4*)cmb)[id] = v;
}

// One block = one window; 256 threads = 4 waves; wave = head h, ALL 64 tokens.
// K and Q stay entirely in registers; V self-produced/consumed via private vtm
// slice; 3 barriers total. __launch_bounds__(256,2): 256-VGPR budget so the
// compiler can keep a whole phase's weight/cmb loads in flight (the R8/R9
// lesson: per-wave ILP, not occupancy, is the binding constraint; R9's (256,4)
// 128-reg budget force-spilled this same structure).
// LDS 34816 B: xb [64][136] (aliased by aom after B2) + vtm [4][32][68].
__global__ __launch_bounds__(256, 2)
void win_attn_kernel(const float* __restrict__ x,
                     const float* __restrict__ qkv_b,
                     const float* __restrict__ proj_b,
                     const short* __restrict__ wq,
                     const short* __restrict__ wp,
                     const float* __restrict__ cmb,
                     float* __restrict__ out) {
  __shared__ __align__(16) short smem[17408];
  short* xb  = smem;            // [64][136]
  short* vtm = smem + 8704;     // [4][32][68] v^T per head: row=d, col=token
  short* aom = smem;            // ALIAS xb: [64][136] after barrier B2

  const int b    = blockIdx.x;
  const int tid  = threadIdx.x;
  const int lane = tid & 63;
  const int h    = tid >> 6;    // wave index = head
  const int l15  = lane & 15;
  const int lhi  = lane >> 4;
  const int cb   = lhi * 8;

  // ---- Phase 0: stage x -> bf16 LDS, zero pad rows 49..63
  {
    short4v z = {0, 0, 0, 0};
    for (int idx = tid; idx < 510; idx += 256)
      *(short4v*)&xb[49 * 136 + idx * 4] = z;
    const float* xw = x + (long)b * (49 * 128);
    for (int idx = tid; idx < 1568; idx += 256) {
      int m  = idx >> 5;
      int c0 = (idx & 31) << 2;
      float4v v = *(const float4v*)&xw[m * 128 + c0];
      short4v s;
      s[0] = f2bf(v[0]); s[1] = f2bf(v[1]); s[2] = f2bf(v[2]); s[3] = f2bf(v[3]);
      *(short4v*)&xb[m * 136 + c0] = s;
    }
  }
  __syncthreads();   // B1

  // ---- Phase 1a: Q+K projection (swapped: acc = [wcol][token]), 64 tokens.
  short8v qfr[4], kfr[4];
  {
    f32x4 qa[2][4], ka[2][4];   // [nt][jt]
#pragma unroll
    for (int nt = 0; nt < 2; ++nt) {
      const f32x4 bq4 = *(const f32x4*)&qkv_b[h * 32 + nt * 16 + lhi * 4];
      const f32x4 bk4 = *(const f32x4*)&qkv_b[128 + h * 32 + nt * 16 + lhi * 4];
#pragma unroll
      for (int jt = 0; jt < 4; ++jt) { qa[nt][jt] = bq4; ka[nt][jt] = bk4; }
    }
#pragma unroll
    for (int ks = 0; ks < 4; ++ks) {
      short8v a[4];
#pragma unroll
      for (int jt = 0; jt < 4; ++jt)
        a[jt] = *(const short8v*)&xb[(jt * 16 + l15) * 136 + ks * 32 + cb];
#pragma unroll
      for (int nt = 0; nt < 2; ++nt) {
        const short8v bq =
            *(const short8v*)&wq[(h * 32 + nt * 16 + l15) * 128 + ks * 32 + cb];
        const short8v bk =
            *(const short8v*)&wq[(128 + h * 32 + nt * 16 + l15) * 128 + ks * 32 + cb];
#pragma unroll
        for (int jt = 0; jt < 4; ++jt) {
          qa[nt][jt] = mfma16(bq, a[jt], qa[nt][jt]);
          ka[nt][jt] = mfma16(bk, a[jt], ka[nt][jt]);
        }
      }
    }
    const float scale = 0.1767766952966369f;  // 32^-0.5
#pragma unroll
    for (int jt = 0; jt < 4; ++jt) {
      short8v qv, kv;
#pragma unroll
      for (int nt = 0; nt < 2; ++nt)
#pragma unroll
        for (int r = 0; r < 4; ++r) {
          qv[nt * 4 + r] = f2bf(qa[nt][jt][r] * scale);
          kv[nt * 4 + r] = f2bf(ka[nt][jt][r]);
        }
      qfr[jt] = qv;
      kfr[jt] = kv;
    }
  }

  // ---- Phase 1b: V projection (normal), store transposed to OWN vtm slice.
  {
    f32x4 va[2][4];   // [nt][mt]
#pragma unroll
    for (int nt = 0; nt < 2; ++nt) {
      const float vb = qkv_b[256 + h * 32 + nt * 16 + l15];
#pragma unroll
      for (int mt = 0; mt < 4; ++mt) va[nt][mt] = f32x4{vb, vb, vb, vb};
    }
#pragma unroll
    for (int ks = 0; ks < 4; ++ks) {
      short8v a[4];
#pragma unroll
      for (int mt = 0; mt < 4; ++mt)
        a[mt] = *(const short8v*)&xb[(mt * 16 + l15) * 136 + ks * 32 + cb];
#pragma unroll
      for (int nt = 0; nt < 2; ++nt) {
        const short8v bv =
            *(const short8v*)&wq[(256 + h * 32 + nt * 16 + l15) * 128 + ks * 32 + cb];
#pragma unroll
        for (int mt = 0; mt < 4; ++mt)
          va[nt][mt] = mfma16(a[mt], bv, va[nt][mt]);
      }
    }
#pragma unroll
    for (int nt = 0; nt < 2; ++nt)
#pragma unroll
      for (int mt = 0; mt < 4; ++mt) {
        short4v p;
#pragma unroll
        for (int r = 0; r < 4; ++r) p[r] = f2bf(va[nt][mt][r]);
        *(short4v*)&vtm[h * 2176 + (nt * 16 + l15) * 68 + mt * 16 + lhi * 4] = p;
      }
  }
  // vtm slice is private to this wave: no barrier (in-wave lgkmcnt ordering).

  // ---- Phase 2: S = mfma(K,Q) + cmb; softmax in-lane; PV into registers.
  f32x4 o[2][4];    // [dt][jt]
#pragma unroll
  for (int dt = 0; dt < 2; ++dt)
#pragma unroll
    for (int jt = 0; jt < 4; ++jt) o[dt][jt] = f32x4{0.f, 0.f, 0.f, 0.f};
  {
    const f32x4* cmb4 = (const f32x4*)cmb;
    const long cbase = (long)(b & 63) * 4096 + h * 1024 + lane;

#pragma unroll
    for (int jt = 0; jt < 4; ++jt) {
      f32x4 s[4];
#pragma unroll
      for (int i = 0; i < 4; ++i)
        s[i] = mfma16(kfr[i], qfr[jt], cmb4[cbase + jt * 256 + i * 64]);

      float mx = s[0][0];
#pragma unroll
      for (int i = 0; i < 4; ++i)
#pragma unroll
        for (int r = 0; r < 4; ++r) mx = fmaxf(mx, s[i][r]);
      mx = fmaxf(mx, __shfl_xor(mx, 16));
      mx = fmaxf(mx, __shfl_xor(mx, 32));
      float sum = 0.f;
#pragma unroll
      for (int i = 0; i < 4; ++i)
#pragma unroll
        for (int r = 0; r < 4; ++r) {
          float e = __expf(s[i][r] - mx);
          s[i][r] = e;
          sum += e;
        }
      sum += __shfl_xor(sum, 16);
      sum += __shfl_xor(sum, 32);
      const float inv = 1.f / sum;

      short8v pb[2];
#pragma unroll
      for (int ks = 0; ks < 2; ++ks) {
        short8v pv;
#pragma unroll
        for (int e = 0; e < 4; ++e) pv[e]     = f2bf(s[2 * ks][e] * inv);
#pragma unroll
        for (int e = 0; e < 4; ++e) pv[4 + e] = f2bf(s[2 * ks + 1][e] * inv);
        pb[ks] = pv;
      }

#pragma unroll
      for (int dt = 0; dt < 2; ++dt)
#pragma unroll
        for (int ks = 0; ks < 2; ++ks) {
          const int va = h * 2176 + (dt * 16 + l15) * 68 + ks * 32 + lhi * 4;
          short8v vfr = cat44(*(const short4v*)&vtm[va], *(const short4v*)&vtm[va + 16]);
          o[dt][jt] = mfma16(vfr, pb[ks], o[dt][jt]);
        }
    }
  }
  __syncthreads();   // B2: all xb reads done; aom may overwrite xb

#pragma unroll
  for (int dt = 0; dt < 2; ++dt)
#pragma unroll
    for (int jt = 0; jt < 4; ++jt) {
      short4v p;
#pragma unroll
      for (int r = 0; r < 4; ++r) p[r] = f2bf(o[dt][jt][r]);
      *(short4v*)&aom[(jt * 16 + l15) * 136 + h * 32 + dt * 16 + lhi * 4] = p;
    }
  __syncthreads();   // B3: aom complete

  // ---- Phase 3: output projection Y = AO @ proj_w^T + proj_b (ks-outer)
  {
    f32x4 po[2][4];   // [nt][mt]
#pragma unroll
    for (int nt = 0; nt < 2; ++nt) {
      const float pbv = proj_b[h * 32 + nt * 16 + l15];
#pragma unroll
      for (int mt = 0; mt < 4; ++mt) po[nt][mt] = f32x4{pbv, pbv, pbv, pbv};
    }
#pragma unroll
    for (int ks = 0; ks < 4; ++ks) {
      short8v p[4];
#pragma unroll
      for (int mt = 0; mt < 4; ++mt)
        p[mt] = *(const short8v*)&aom[(mt * 16 + l15) * 136 + ks * 32 + cb];
#pragma unroll
      for (int nt = 0; nt < 2; ++nt) {
        const short8v wfr =
            *(const short8v*)&wp[(h * 32 + nt * 16 + l15) * 128 + ks * 32 + cb];
#pragma unroll
        for (int mt = 0; mt < 4; ++mt)
          po[nt][mt] = mfma16(p[mt], wfr, po[nt][mt]);
      }
    }
    float* outw = out + (long)b * (49 * 128);
#pragma unroll
    for (int nt = 0; nt < 2; ++nt) {
      const int ncol = h * 32 + nt * 16 + l15;
#pragma unroll
      for (int mt = 0; mt < 4; ++mt)
#pragma unroll
        for (int r = 0; r < 4; ++r) {
          const int m0 = mt * 16 + lhi * 4 + r;
          if (m0 < 49) outw[m0 * 128 + ncol] = po[nt][mt][r];
        }
    }
  }
}

extern "C" void kernel_launch(void* const* d_in, const int* in_sizes, int n_in,
                              void* d_out, int out_size, void* d_ws, size_t ws_size,
                              hipStream_t stream) {
  const float* x          = (const float*)d_in[0];
  const float* mask       = (const float*)d_in[1];
  const float* qkv_w      = (const float*)d_in[2];
  const float* qkv_b      = (const float*)d_in[3];
  const float* proj_w     = (const float*)d_in[4];
  const float* proj_b     = (const float*)d_in[5];
  const float* bias_table = (const float*)d_in[6];

  short* wq  = (short*)d_ws;                         // 384*128 bf16 (98304 B)
  short* wp  = wq + 49152;                           // 128*128 bf16 (32768 B)
  float* cmb = (float*)((char*)d_ws + 131072);       // 4 MB combined bias+mask

  cvt_weights_kernel<<<dim3(192), dim3(256), 0, stream>>>(qkv_w, proj_w, wq, wp);
  build_cmb_kernel<<<dim3(1024), dim3(256), 0, stream>>>(mask, bias_table, cmb);
  win_attn_kernel<<<dim3(4096), dim3(256), 0, stream>>>(
      x, qkv_b, proj_b, wq, wp, cmb, (float*)d_out);
}